// Round 7
// baseline (1024.169 us; speedup 1.0000x reference)
//
#include <hip/hip_runtime.h>
#include <hip/hip_fp16.h>
#include <cstddef>

#define NA 200000
#define NE 3200000
#define NB 512
#define NBKT 256          // dst-range buckets
#define BKTN 782          // nodes per bucket
#define BKTCAP 16384      // stage capacity per bucket (exp 12500, sigma ~111)
#define NEPB 3200         // edges per pass-1 block (1000*3200 = NE)

// ---------------- fp16 helpers: 4 halves <-> float4 ----------------
union UH2 { unsigned u; __half2 h; };
__device__ __forceinline__ float4 h4f(uint2 v) {
    UH2 a, b; a.u = v.x; b.u = v.y;
    float2 fa = __half22float2(a.h), fb = __half22float2(b.h);
    return make_float4(fa.x, fa.y, fb.x, fb.y);
}
__device__ __forceinline__ unsigned f2h(float a, float b) {
    UH2 r; r.h = __float22half2_rn(make_float2(a, b));
    return r.u;
}

// ---------------- init: g=0 (8192), gcursor[b]=b*BKTCAP ----------------
__global__ void k_init(unsigned* g, int* gcursor) {
    int i = blockIdx.x * blockDim.x + threadIdx.x;
    if (i < NB * 16) g[i] = 0u;
    if (i < NBKT) gcursor[i] = i * BKTCAP;
}

// ---- pass 1: bin edges into 256 dst-range buckets (LDS hist), payload
// (dstLocal<<18 | src), src<2^18; int4-vectorized edge reads ----
__global__ __launch_bounds__(256) void k_pass1(
        const int* __restrict__ src, const int* __restrict__ dst,
        int* __restrict__ gcursor, unsigned* __restrict__ stage) {
    __shared__ int hcnt[NBKT];
    __shared__ int hbase[NBKT];
    int e0 = blockIdx.x * NEPB;
    hcnt[threadIdx.x] = 0;
    __syncthreads();
    const int4* d4 = (const int4*)(dst + e0);
    for (int i = threadIdx.x; i < NEPB / 4; i += 256) {
        int4 d = d4[i];
        atomicAdd(&hcnt[d.x / BKTN], 1);
        atomicAdd(&hcnt[d.y / BKTN], 1);
        atomicAdd(&hcnt[d.z / BKTN], 1);
        atomicAdd(&hcnt[d.w / BKTN], 1);
    }
    __syncthreads();
    hbase[threadIdx.x] = atomicAdd(&gcursor[threadIdx.x], hcnt[threadIdx.x]);
    hcnt[threadIdx.x] = 0;
    __syncthreads();
    const int4* s4 = (const int4*)(src + e0);
    for (int i = threadIdx.x; i < NEPB / 4; i += 256) {
        int4 d = d4[i];
        int4 s = s4[i];
        int ds[4] = {d.x, d.y, d.z, d.w};
        int ss[4] = {s.x, s.y, s.z, s.w};
#pragma unroll
        for (int j = 0; j < 4; j++) {
            int bkt = ds[j] / BKTN;
            int dloc = ds[j] - bkt * BKTN;
            int k = atomicAdd(&hcnt[bkt], 1);
            stage[hbase[bkt] + k] = ((unsigned)dloc << 18) | (unsigned)ss[j];
        }
    }
}

// ---- pass 2: per-bucket count + scan + scatter into compact CSR;
// bucket base computed inline; also emits ht1 = dis*(x@W1) in fp16 ----
__global__ __launch_bounds__(256) void k_pass2(
        const unsigned* __restrict__ stage, const int* __restrict__ gcursor,
        int* __restrict__ rowptr, int* __restrict__ cnt, int* __restrict__ csr,
        const float* __restrict__ x, const float* __restrict__ W1,
        uint2* __restrict__ ht1) {
    __shared__ int lcnt[BKTN];
    __shared__ int lpos[BKTN];
    __shared__ int partial[256];
    __shared__ float sW1[16];
    __shared__ int sbase;
    int t = threadIdx.x;
    int bkt = blockIdx.x;
    if (t < 16) sW1[t] = W1[t];
    // bucket-base scan (replicated per block)
    int tot = gcursor[t] - t * BKTCAP;
    partial[t] = tot;
    __syncthreads();
#pragma unroll
    for (int off = 1; off < 256; off <<= 1) {
        int u = (t >= off) ? partial[t - off] : 0;
        __syncthreads();
        partial[t] += u;
        __syncthreads();
    }
    if (t == 0) sbase = (bkt == 0) ? 0 : partial[bkt - 1];
    __syncthreads();
    int base = sbase;
    int n0 = bkt * BKTN;
    int ncnt = (NA - n0 < BKTN) ? (NA - n0) : BKTN;
    int eBeg = bkt * BKTCAP;
    int eCnt = gcursor[bkt] - eBeg;
    for (int i = t; i < BKTN; i += 256) lcnt[i] = 0;
    __syncthreads();
    for (int i = t; i < eCnt; i += 256)
        atomicAdd(&lcnt[stage[eBeg + i] >> 18], 1);
    __syncthreads();
    // node scan: thread t owns nodes [4t, 4t+4)
    int mysum = 0;
#pragma unroll
    for (int j = 0; j < 4; j++) {
        int node = 4 * t + j;
        if (node < ncnt) mysum += lcnt[node];
    }
    partial[t] = mysum;
    __syncthreads();
#pragma unroll
    for (int off = 1; off < 256; off <<= 1) {
        int u = (t >= off) ? partial[t - off] : 0;
        __syncthreads();
        partial[t] += u;
        __syncthreads();
    }
    int running = partial[t] - mysum;
#pragma unroll
    for (int j = 0; j < 4; j++) {
        int node = 4 * t + j;
        if (node < ncnt) {
            lpos[node] = running;
            rowptr[n0 + node] = base + running;
            cnt[n0 + node] = lcnt[node];
            running += lcnt[node];
        }
    }
    __syncthreads();
    for (int i = t; i < eCnt; i += 256) {
        unsigned v = stage[eBeg + i];
        int dloc = v >> 18;
        int s = v & 0x3FFFF;
        int k = atomicAdd(&lpos[dloc], 1);
        csr[base + k] = s;
    }
    // ht1 (lcnt stable; no barrier needed)
    for (int i = t; i < ncnt; i += 256) {
        int n = n0 + i;
        float4 p = ((const float4*)x)[n];
        float dv = rsqrtf((float)lcnt[i] + 1.0f);
        float o0 = dv * (p.x * sW1[0] + p.y * sW1[4]  + p.z * sW1[8]  + p.w * sW1[12]);
        float o1 = dv * (p.x * sW1[1] + p.y * sW1[5]  + p.z * sW1[9]  + p.w * sW1[13]);
        float o2 = dv * (p.x * sW1[2] + p.y * sW1[6]  + p.z * sW1[10] + p.w * sW1[14]);
        float o3 = dv * (p.x * sW1[3] + p.y * sW1[7]  + p.z * sW1[11] + p.w * sW1[15]);
        ht1[n] = make_uint2(f2h(o0, o1), f2h(o2, o3));
    }
}

// ---------------- conv1 device body (untiled, transpose load) --------------
template<int CIN, int COUT, int OBLK, int LIN, int PITCH, int POUT, int NTT>
__device__ __forceinline__ void dev_conv1(int b, int oy,
        const float* __restrict__ in, const float* __restrict__ Kw,
        const float* __restrict__ bias, float* __restrict__ out) {
    constexpr int SPO = 256 / OBLK;
    constexpr int PT = (NTT < 4) ? NTT : 4;
    constexpr int NPASS = (NTT + PT - 1) / PT;
    __shared__ __align__(16) float s_in[CIN * PITCH];
    for (int idx = threadIdx.x; idx < CIN * PITCH; idx += 256) s_in[idx] = 0.f;
    __syncthreads();
    for (int idx = threadIdx.x; idx < LIN * CIN; idx += 256) {
        int p = idx / CIN, c = idx - p * CIN;
        s_in[c * PITCH + p] = in[(size_t)b * (LIN * CIN) + idx];
    }
    __syncthreads();
    int ol = threadIdx.x / SPO;
    int s  = threadIdx.x - ol * SPO;
    int o  = oy * OBLK + ol;
    float bo = bias[o];
    const float* wrow = Kw + (size_t)o * CIN * 8;
    for (int pass = 0; pass < NPASS; pass++) {
        float acc[PT][12];
#pragma unroll
        for (int tt = 0; tt < PT; tt++)
#pragma unroll
            for (int j = 0; j < 12; j++) acc[tt][j] = 0.f;
        bool vld[PT]; int tgs[PT];
#pragma unroll
        for (int tt = 0; tt < PT; tt++) {
            int ta = pass * PT + tt;
            int tg = s + SPO * ta;
            tgs[tt] = tg;
            vld[tt] = (ta < NTT) && (4 * tg < POUT);
        }
        for (int i = 0; i < CIN; i++) {
            float wa[8];
            const float4* wp = (const float4*)(wrow + (size_t)i * 8);
            *(float4*)&wa[0] = wp[0];
            *(float4*)&wa[4] = wp[1];
#pragma unroll
            for (int tt = 0; tt < PT; tt++) {
                if (vld[tt]) {
                    const float4* xr = (const float4*)&s_in[i * PITCH + 12 * tgs[tt]];
                    float xa[20];
#pragma unroll
                    for (int q = 0; q < 5; q++) *(float4*)&xa[4 * q] = xr[q];
#pragma unroll
                    for (int j = 0; j < 12; j++) {
                        float sm = acc[tt][j];
#pragma unroll
                        for (int k = 0; k < 8; k++) sm = fmaf(xa[j + k], wa[k], sm);
                        acc[tt][j] = sm;
                    }
                }
            }
        }
#pragma unroll
        for (int tt = 0; tt < PT; tt++) {
            if (vld[tt]) {
#pragma unroll
                for (int p = 0; p < 4; p++) {
                    int P = 4 * tgs[tt] + p;
                    if (P < POUT) {
                        float m = fmaxf(fmaxf(acc[tt][3 * p], acc[tt][3 * p + 1]), acc[tt][3 * p + 2]);
                        out[((size_t)b * COUT + o) * POUT + P] = fmaxf(m + bo, 0.f);
                    }
                }
            }
        }
    }
}

// ------------- tiled conv device body (seq-axis tiles, small LDS) ----------
template<int CIN, int COUT, int OBLK, int LIN, int PITCH, int TPOOL, int POUT>
__device__ __forceinline__ void dev_conv_t(int b, int oy, int tile,
        const float* __restrict__ in, const float* __restrict__ Kw,
        const float* __restrict__ bias, float* __restrict__ out) {
    constexpr int SPO = 256 / OBLK;
    constexpr int NQ = TPOOL / 4;
    constexpr int NTT = (NQ + SPO - 1) / SPO;
    constexpr int SPAN = 3 * TPOOL + 7;
    __shared__ __align__(16) float s_in[CIN * PITCH];
    int p0 = tile * TPOOL;
    int cbase = 3 * p0;
    for (int idx = threadIdx.x; idx < CIN * PITCH; idx += 256) {
        int c = idx / PITCH, p = idx - c * PITCH;
        int gp = cbase + p;
        float v = 0.f;
        if (p < SPAN && gp < LIN) v = in[((size_t)b * CIN + c) * LIN + gp];
        s_in[idx] = v;
    }
    __syncthreads();
    int ol = threadIdx.x / SPO;
    int s  = threadIdx.x - ol * SPO;
    int o  = oy * OBLK + ol;
    float bo = bias[o];
    const float* wrow = Kw + (size_t)o * CIN * 8;
    float acc[NTT][12];
#pragma unroll
    for (int tt = 0; tt < NTT; tt++)
#pragma unroll
        for (int j = 0; j < 12; j++) acc[tt][j] = 0.f;
    bool vld[NTT]; int qgs[NTT];
#pragma unroll
    for (int tt = 0; tt < NTT; tt++) {
        int qg = s + SPO * tt;
        qgs[tt] = qg;
        vld[tt] = (qg < NQ) && (p0 + 4 * qg < POUT);
    }
    for (int i = 0; i < CIN; i++) {
        float wa[8];
        const float4* wp = (const float4*)(wrow + (size_t)i * 8);
        *(float4*)&wa[0] = wp[0];
        *(float4*)&wa[4] = wp[1];
#pragma unroll
        for (int tt = 0; tt < NTT; tt++) {
            if (vld[tt]) {
                const float4* xr = (const float4*)&s_in[i * PITCH + 12 * qgs[tt]];
                float xa[20];
#pragma unroll
                for (int q = 0; q < 5; q++) *(float4*)&xa[4 * q] = xr[q];
#pragma unroll
                for (int j = 0; j < 12; j++) {
                    float sm = acc[tt][j];
#pragma unroll
                    for (int k = 0; k < 8; k++) sm = fmaf(xa[j + k], wa[k], sm);
                    acc[tt][j] = sm;
                }
            }
        }
    }
#pragma unroll
    for (int tt = 0; tt < NTT; tt++) {
        if (vld[tt]) {
#pragma unroll
            for (int p = 0; p < 4; p++) {
                int P = p0 + 4 * qgs[tt] + p;
                if (P < POUT) {
                    float m = fmaxf(fmaxf(acc[tt][3 * p], acc[tt][3 * p + 1]), acc[tt][3 * p + 2]);
                    out[((size_t)b * COUT + o) * POUT + P] = fmaxf(m + bo, 0.f);
                }
            }
        }
    }
}

// -------- K_B (striped): gather1+transform2 (782) || conv1 (1024) ----------
__global__ __launch_bounds__(256) void k_fused_B(
        const float* __restrict__ tgt, const float* __restrict__ K1,
        const float* __restrict__ cb1, float* __restrict__ pool1,
        const uint2* __restrict__ ht1, const int* __restrict__ rowptr,
        const int* __restrict__ cnt, const int* __restrict__ csr,
        const float* __restrict__ b1, const float* __restrict__ W2,
        uint4* __restrict__ ht2) {
    int bx = blockIdx.x;
    int id; bool conv;
    if (bx < 1564) { conv = (bx & 1) != 0; id = bx >> 1; }
    else { conv = true; id = 782 + (bx - 1564); }
    if (conv) {
        dev_conv1<5, 32, 16, 1000, 1008, 331, 6>(id & 511, id >> 9, tgt, K1, cb1, pool1);
        return;
    }
    __shared__ float sW2[32];
    if (threadIdx.x < 32) sW2[threadIdx.x] = W2[threadIdx.x];
    __syncthreads();
    int n = id * 256 + threadIdx.x;
    if (n >= NA) return;
    int cn = cnt[n];
    float dv = rsqrtf((float)cn + 1.0f);
    const int* row = csr + rowptr[n];
    float4 acc = h4f(ht1[n]);
    int e = 0;
    for (; e + 3 < cn; e += 4) {
        int i0 = row[e], i1 = row[e + 1], i2 = row[e + 2], i3 = row[e + 3];
        float4 v0 = h4f(ht1[i0]), v1 = h4f(ht1[i1]);
        float4 v2 = h4f(ht1[i2]), v3 = h4f(ht1[i3]);
        acc.x += (v0.x + v1.x) + (v2.x + v3.x);
        acc.y += (v0.y + v1.y) + (v2.y + v3.y);
        acc.z += (v0.z + v1.z) + (v2.z + v3.z);
        acc.w += (v0.w + v1.w) + (v2.w + v3.w);
    }
    for (; e < cn; e++) {
        float4 v = h4f(ht1[row[e]]);
        acc.x += v.x; acc.y += v.y; acc.z += v.z; acc.w += v.w;
    }
    const float4 bq = *(const float4*)b1;
    float r[4];
    r[0] = fmaxf(fmaf(dv, acc.x, bq.x), 0.f);
    r[1] = fmaxf(fmaf(dv, acc.y, bq.y), 0.f);
    r[2] = fmaxf(fmaf(dv, acc.z, bq.z), 0.f);
    r[3] = fmaxf(fmaf(dv, acc.w, bq.w), 0.f);
    float o[8];
#pragma unroll
    for (int f = 0; f < 8; f++) {
        float s = 0.f;
#pragma unroll
        for (int k = 0; k < 4; k++) s = fmaf(r[k], sW2[k * 8 + f], s);
        o[f] = dv * s;
    }
    ht2[n] = make_uint4(f2h(o[0], o[1]), f2h(o[2], o[3]), f2h(o[4], o[5]), f2h(o[6], o[7]));
}

// -------- K_C (striped): gather2+transform3 (1563) || conv2 tiled (1536) ---
__global__ __launch_bounds__(256) void k_fused_C(
        const float* __restrict__ pool1, const float* __restrict__ K2,
        const float* __restrict__ cb2, float* __restrict__ pool2,
        const uint2* __restrict__ ht2, const int* __restrict__ rowptr,
        const int* __restrict__ cnt, const int* __restrict__ csr,
        const float* __restrict__ b2, const float* __restrict__ W3,
        uint4* __restrict__ ht3) {
    int bx = blockIdx.x;
    int id; bool conv;
    if (bx < 3072) { conv = (bx & 1) == 0; id = bx >> 1; }
    else { conv = false; id = 1536 + (bx - 3072); }
    if (conv) {
        dev_conv_t<32, 64, 64, 331, 116, 36, 108>(id & 511, 0, id >> 9, pool1, K2, cb2, pool2);
        return;
    }
    __shared__ float sW3[128];
    if (threadIdx.x < 128) sW3[threadIdx.x] = W3[threadIdx.x];
    __syncthreads();
    int t = id * 256 + threadIdx.x;
    int n = t >> 1, q = t & 1;
    if (n >= NA) return;
    int cn = cnt[n];
    float dv = rsqrtf((float)cn + 1.0f);
    const int* row = csr + rowptr[n];
    float4 acc = h4f(ht2[(size_t)n * 2 + q]);
    int e = 0;
    for (; e + 3 < cn; e += 4) {
        int i0 = row[e], i1 = row[e + 1], i2 = row[e + 2], i3 = row[e + 3];
        float4 v0 = h4f(ht2[(size_t)i0 * 2 + q]), v1 = h4f(ht2[(size_t)i1 * 2 + q]);
        float4 v2 = h4f(ht2[(size_t)i2 * 2 + q]), v3 = h4f(ht2[(size_t)i3 * 2 + q]);
        acc.x += (v0.x + v1.x) + (v2.x + v3.x);
        acc.y += (v0.y + v1.y) + (v2.y + v3.y);
        acc.z += (v0.z + v1.z) + (v2.z + v3.z);
        acc.w += (v0.w + v1.w) + (v2.w + v3.w);
    }
    for (; e < cn; e++) {
        float4 v = h4f(ht2[(size_t)row[e] * 2 + q]);
        acc.x += v.x; acc.y += v.y; acc.z += v.z; acc.w += v.w;
    }
    const float4 bq = *(const float4*)(b2 + q * 4);
    float r[4];
    r[0] = fmaxf(fmaf(dv, acc.x, bq.x), 0.f);
    r[1] = fmaxf(fmaf(dv, acc.y, bq.y), 0.f);
    r[2] = fmaxf(fmaf(dv, acc.z, bq.z), 0.f);
    r[3] = fmaxf(fmaf(dv, acc.w, bq.w), 0.f);
    float other[4];
#pragma unroll
    for (int j = 0; j < 4; j++) other[j] = __shfl_xor(r[j], 1, 64);
    float rf[8];
    if (q == 0) {
#pragma unroll
        for (int j = 0; j < 4; j++) { rf[j] = r[j]; rf[4 + j] = other[j]; }
    } else {
#pragma unroll
        for (int j = 0; j < 4; j++) { rf[j] = other[j]; rf[4 + j] = r[j]; }
    }
    float o[8];
#pragma unroll
    for (int f = 0; f < 8; f++) {
        float s = 0.f;
#pragma unroll
        for (int k = 0; k < 8; k++) s = fmaf(rf[k], sW3[k * 16 + q * 8 + f], s);
        o[f] = dv * s;
    }
    ht3[(size_t)n * 2 + q] =
        make_uint4(f2h(o[0], o[1]), f2h(o[2], o[3]), f2h(o[4], o[5]), f2h(o[6], o[7]));
}

// -------- K_D (striped 3:1): gather3+segmax (3125) || conv3 tiled (1024) ---
__global__ __launch_bounds__(256) void k_fused_D(
        const float* __restrict__ pool2, const float* __restrict__ K3,
        const float* __restrict__ cb3, float* __restrict__ pool3,
        const uint2* __restrict__ ht3, const int* __restrict__ rowptr,
        const int* __restrict__ cnt, const int* __restrict__ csr,
        const float* __restrict__ b3, const int* __restrict__ batch,
        unsigned* __restrict__ g) {
    int bx = blockIdx.x;
    int id; bool conv;
    if (bx < 4096) {
        conv = (bx & 3) == 3;
        id = conv ? (bx >> 2) : (3 * (bx >> 2) + (bx & 3));
    } else { conv = false; id = 3072 + (bx - 4096); }
    if (conv) {
        dev_conv_t<64, 128, 128, 108, 68, 20, 33>(id & 511, 0, id >> 9, pool2, K3, cb3, pool3);
        return;
    }
    __shared__ unsigned sg[32];
    __shared__ int sbmin;
    if (threadIdx.x < 32) sg[threadIdx.x] = 0u;
    if (threadIdx.x == 0) sbmin = batch[id * 64];
    __syncthreads();
    int t = id * 256 + threadIdx.x;        // 3125*256 == NA*4 exactly
    int n = t >> 2, q = t & 3;
    int cn = cnt[n];
    float dv = rsqrtf((float)cn + 1.0f);
    const int* row = csr + rowptr[n];
    float4 acc = h4f(ht3[(size_t)n * 4 + q]);
    int e = 0;
    for (; e + 3 < cn; e += 4) {
        int i0 = row[e], i1 = row[e + 1], i2 = row[e + 2], i3 = row[e + 3];
        float4 v0 = h4f(ht3[(size_t)i0 * 4 + q]), v1 = h4f(ht3[(size_t)i1 * 4 + q]);
        float4 v2 = h4f(ht3[(size_t)i2 * 4 + q]), v3 = h4f(ht3[(size_t)i3 * 4 + q]);
        acc.x += (v0.x + v1.x) + (v2.x + v3.x);
        acc.y += (v0.y + v1.y) + (v2.y + v3.y);
        acc.z += (v0.z + v1.z) + (v2.z + v3.z);
        acc.w += (v0.w + v1.w) + (v2.w + v3.w);
    }
    for (; e < cn; e++) {
        float4 v = h4f(ht3[(size_t)row[e] * 4 + q]);
        acc.x += v.x; acc.y += v.y; acc.z += v.z; acc.w += v.w;
    }
    const float4 bq = *(const float4*)(b3 + q * 4);
    float r0 = fmaxf(fmaf(dv, acc.x, bq.x), 0.f);
    float r1 = fmaxf(fmaf(dv, acc.y, bq.y), 0.f);
    float r2 = fmaxf(fmaf(dv, acc.z, bq.z), 0.f);
    float r3 = fmaxf(fmaf(dv, acc.w, bq.w), 0.f);
    int rb = batch[n] - sbmin;
    if (rb > 1) rb = 1;
    atomicMax(&sg[rb * 16 + q * 4 + 0], __float_as_uint(r0));
    atomicMax(&sg[rb * 16 + q * 4 + 1], __float_as_uint(r1));
    atomicMax(&sg[rb * 16 + q * 4 + 2], __float_as_uint(r2));
    atomicMax(&sg[rb * 16 + q * 4 + 3], __float_as_uint(r3));
    __syncthreads();
    if (threadIdx.x < 32) {
        unsigned v = sg[threadIdx.x];
        int rb2 = threadIdx.x >> 4, f = threadIdx.x & 15;
        int bbn = sbmin + rb2;
        if (v != 0u && bbn < NB) atomicMax(&g[bbn * 16 + f], v);
    }
}

// -------- head1: (g@Wg1 -> gp1, 256 blk) || (mean->@Wxt -> cx, 64 blk) -----
__global__ __launch_bounds__(256) void k_head1(
        const float* __restrict__ g, const float* __restrict__ Wg1,
        const float* __restrict__ bg1, float* __restrict__ gp1,
        const float* __restrict__ pool3, const float* __restrict__ Wxt,
        const float* __restrict__ bxt, float* __restrict__ cx) {
    int bx = blockIdx.x;
    if (bx < 256) {
        __shared__ float sa[8 * 16];
        int b0 = (bx >> 2) * 8;
        if (threadIdx.x < 128)
            sa[threadIdx.x] = g[b0 * 16 + threadIdx.x];
        __syncthreads();
        int j = (bx & 3) * 256 + threadIdx.x;
        float bj = bg1[j];
        float acc[8];
#pragma unroll
        for (int gg = 0; gg < 8; gg++) acc[gg] = bj;
#pragma unroll
        for (int k = 0; k < 16; k++) {
            float w = Wg1[(size_t)k * 1024 + j];
#pragma unroll
            for (int gg = 0; gg < 8; gg++) acc[gg] = fmaf(sa[gg * 16 + k], w, acc[gg]);
        }
#pragma unroll
        for (int gg = 0; gg < 8; gg++)
            gp1[(size_t)(b0 + gg) * 1024 + j] = fmaxf(acc[gg], 0.f);
    } else {
        __shared__ float sa[8 * 128];
        int b0 = (bx - 256) * 8;
        for (int t = threadIdx.x; t < 8 * 128; t += 256) {
            int gg = t >> 7, k = t & 127;
            const float* r = pool3 + ((size_t)(b0 + gg) * 128 + k) * 33;
            float s = 0.f;
#pragma unroll
            for (int p = 0; p < 33; p++) s += r[p];
            sa[t] = s * (1.f / 33.f);
        }
        __syncthreads();
        int j = threadIdx.x;
        if (j >= 128) return;
        float bj = bxt[j];
        float acc[8];
#pragma unroll
        for (int gg = 0; gg < 8; gg++) acc[gg] = bj;
#pragma unroll 4
        for (int k = 0; k < 128; k++) {
            float w = Wxt[(size_t)k * 128 + j];
#pragma unroll
            for (int gg = 0; gg < 8; gg++) acc[gg] = fmaf(sa[gg * 128 + k], w, acc[gg]);
        }
#pragma unroll
        for (int gg = 0; gg < 8; gg++)
            cx[(size_t)(b0 + gg) * 128 + j] = fmaxf(acc[gg], 0.f);
    }
}

// ------- batch-grouped dense: BGRP rows share one pass over W --------------
template<int K, int BGRP, bool RELU>
__global__ __launch_bounds__(256) void k_dense_g(
        const float* __restrict__ A, const float* __restrict__ W,
        const float* __restrict__ bias, float* __restrict__ out, int ncols) {
    __shared__ float sa[BGRP * K];
    int b0 = blockIdx.y * BGRP;
    for (int t = threadIdx.x; t < BGRP * K; t += 256) {
        int gg = t / K, k = t - gg * K;
        sa[t] = A[(size_t)(b0 + gg) * K + k];
    }
    __syncthreads();
    int j = blockIdx.x * 256 + threadIdx.x;
    if (j >= ncols) return;
    float bj = bias[j];
    float acc[BGRP];
#pragma unroll
    for (int gg = 0; gg < BGRP; gg++) acc[gg] = bj;
#pragma unroll 4
    for (int k = 0; k < K; k++) {
        float w = W[(size_t)k * ncols + j];
#pragma unroll
        for (int gg = 0; gg < BGRP; gg++) acc[gg] = fmaf(sa[gg * K + k], w, acc[gg]);
    }
#pragma unroll
    for (int gg = 0; gg < BGRP; gg++) {
        float v = acc[gg];
        if (RELU) v = fmaxf(v, 0.f);
        out[(size_t)(b0 + gg) * ncols + j] = v;
    }
}

// dense with concatenated input [A1 | A2]
template<int KA, int KB2, int BGRP, bool RELU>
__global__ __launch_bounds__(256) void k_dense_cat_g(
        const float* __restrict__ A1, const float* __restrict__ A2,
        const float* __restrict__ W, const float* __restrict__ bias,
        float* __restrict__ out, int ncols) {
    constexpr int K = KA + KB2;
    __shared__ float sa[BGRP * K];
    int b0 = blockIdx.y * BGRP;
    for (int t = threadIdx.x; t < BGRP * K; t += 256) {
        int gg = t / K, k = t - gg * K;
        sa[t] = (k < KA) ? A1[(size_t)(b0 + gg) * KA + k]
                         : A2[(size_t)(b0 + gg) * KB2 + (k - KA)];
    }
    __syncthreads();
    int j = blockIdx.x * 256 + threadIdx.x;
    if (j >= ncols) return;
    float bj = bias[j];
    float acc[BGRP];
#pragma unroll
    for (int gg = 0; gg < BGRP; gg++) acc[gg] = bj;
#pragma unroll 4
    for (int k = 0; k < K; k++) {
        float w = W[(size_t)k * ncols + j];
#pragma unroll
        for (int gg = 0; gg < BGRP; gg++) acc[gg] = fmaf(sa[gg * K + k], w, acc[gg]);
    }
#pragma unroll
    for (int gg = 0; gg < BGRP; gg++) {
        float v = acc[gg];
        if (RELU) v = fmaxf(v, 0.f);
        out[(size_t)(b0 + gg) * ncols + j] = v;
    }
}

// final 512->2 layer
__global__ __launch_bounds__(256) void k_dense_out(
        const float* __restrict__ A, const float* __restrict__ W,
        const float* __restrict__ bias, float* __restrict__ out) {
    int idx = blockIdx.x * 256 + threadIdx.x;
    if (idx >= NB * 2) return;
    int b = idx >> 1, j = idx & 1;
    float s = bias[j];
#pragma unroll 8
    for (int k = 0; k < 512; k++) s = fmaf(A[b * 512 + k], W[k * 2 + j], s);
    out[idx] = s;
}

extern "C" void kernel_launch(void* const* d_in, const int* in_sizes, int n_in,
                              void* d_out, int out_size, void* d_ws, size_t ws_size,
                              hipStream_t stream) {
    (void)in_sizes; (void)n_in; (void)out_size; (void)ws_size;
    const float* x   = (const float*)d_in[0];
    const int*  ei   = (const int*)d_in[1];
    const int*  batch= (const int*)d_in[2];
    const float* tgt = (const float*)d_in[3];
    const float* W1  = (const float*)d_in[4];  const float* b1  = (const float*)d_in[5];
    const float* W2  = (const float*)d_in[6];  const float* b2  = (const float*)d_in[7];
    const float* W3  = (const float*)d_in[8];  const float* b3  = (const float*)d_in[9];
    const float* Wg1 = (const float*)d_in[10]; const float* bg1 = (const float*)d_in[11];
    const float* Wg2 = (const float*)d_in[12]; const float* bg2 = (const float*)d_in[13];
    const float* K1  = (const float*)d_in[14]; const float* cb1 = (const float*)d_in[15];
    const float* K2  = (const float*)d_in[16]; const float* cb2 = (const float*)d_in[17];
    const float* K3  = (const float*)d_in[18]; const float* cb3 = (const float*)d_in[19];
    const float* Wxt = (const float*)d_in[20]; const float* bxt = (const float*)d_in[21];
    const float* Wf1 = (const float*)d_in[22]; const float* bf1 = (const float*)d_in[23];
    const float* Wf2 = (const float*)d_in[24]; const float* bf2 = (const float*)d_in[25];
    const float* Wo  = (const float*)d_in[26]; const float* bo  = (const float*)d_in[27];
    const int* srcp = ei;        // edge_index[0]
    const int* dstp = ei + NE;   // edge_index[1]

    float* ws = (float*)d_ws;
    uint2* ht1  = (uint2*)ws;  ws += (size_t)NA * 2;        // fp16, 1.6 MB
    uint4* ht2  = (uint4*)ws;  ws += (size_t)NA * 4;        // fp16, 3.2 MB
    uint4* ht3  = (uint4*)ws;  ws += (size_t)NA * 8;        // fp16, 6.4 MB
    float* g     = ws; ws += NB * 16;
    float* gp1   = ws; ws += NB * 1024;
    float* gvec  = ws; ws += NB * 128;
    float* cx    = ws; ws += NB * 128;
    float* xf1   = ws; ws += NB * 1024;
    float* xf2   = ws; ws += NB * 512;
    float* pool1 = ws; ws += (size_t)NB * 32 * 331;   // 5.42M (stage aliases)
    float* pool2 = ws; ws += (size_t)NB * 64 * 108;   // 3.54M
    float* pool3 = ws; ws += (size_t)NB * 128 * 33;   // 2.16M
    int*   cnt    = (int*)ws; ws += NA;
    int*   rowptr = (int*)ws; ws += NA;
    int*   csr    = (int*)ws; ws += NE;               // compact CSR
    int*   gcursor= (int*)ws; ws += NBKT;

    // stage (4.19M u32) aliases pool1: alive pass1->pass2; pool1 written in K_B.
    unsigned* stage = (unsigned*)pool1;

    dim3 blk(256);

    k_init<<<32, blk, 0, stream>>>((unsigned*)g, gcursor);
    k_pass1<<<1000, blk, 0, stream>>>(srcp, dstp, gcursor, stage);
    k_pass2<<<NBKT, blk, 0, stream>>>(stage, gcursor, rowptr, cnt, csr, x, W1, ht1);

    // K_B: gather1+transform2 (782) striped with conv1 (1024)
    k_fused_B<<<1806, blk, 0, stream>>>(tgt, K1, cb1, pool1,
                                        ht1, rowptr, cnt, csr, b1, W2, ht2);
    // K_C: gather2+transform3 (1563) striped with conv2 tiled (1536)
    k_fused_C<<<3099, blk, 0, stream>>>(pool1, K2, cb2, pool2,
                                        (const uint2*)ht2, rowptr, cnt, csr, b2, W3, ht3);
    // K_D: gather3+segmax (3125) striped 3:1 with conv3 tiled (1024)
    k_fused_D<<<4149, blk, 0, stream>>>(pool2, K3, cb3, pool3,
                                        (const uint2*)ht3, rowptr, cnt, csr, b3,
                                        batch, (unsigned*)g);

    // dense head
    k_head1<<<320, blk, 0, stream>>>(g, Wg1, bg1, gp1, pool3, Wxt, bxt, cx);
    k_dense_g<1024, 8, false><<<dim3(1, 64), blk, 0, stream>>>(gp1, Wg2, bg2, gvec, 128);
    k_dense_cat_g<128, 128, 8, true><<<dim3(4, 64), blk, 0, stream>>>(gvec, cx, Wf1, bf1, xf1, 1024);
    k_dense_g<1024, 8, true><<<dim3(2, 64), blk, 0, stream>>>(xf1, Wf2, bf2, xf2, 512);
    k_dense_out<<<4, blk, 0, stream>>>(xf2, Wo, bo, (float*)d_out);
}

// Round 8
// 837.115 us; speedup vs baseline: 1.2235x; 1.2235x over previous
//
#include <hip/hip_runtime.h>
#include <cstddef>

#define NA 200000
#define NE 3200000
#define NB 512
#define NBKT 256          // dst-range buckets
#define BKTN 782          // nodes per bucket
#define BKTCAP 16384      // stage capacity per bucket (exp 12500, sigma ~111)
#define NEPB 3200         // edges per pass-1 block (1000*3200 = NE)

// ---------------- init: g=0, gcursor[b]=b*BKTCAP ----------------
__global__ void k_init(unsigned* g, int* gcursor) {
    int i = blockIdx.x * blockDim.x + threadIdx.x;
    if (i < NB * 16) g[i] = 0u;
    if (i < NBKT) gcursor[i] = i * BKTCAP;
}

// ---- pass 1: bin edges into 256 dst-range buckets (LDS hist), payload
// (dstLocal<<18 | src), src<2^18; int4-vectorized edge reads ----
__global__ __launch_bounds__(256) void k_pass1(
        const int* __restrict__ src, const int* __restrict__ dst,
        int* __restrict__ gcursor, unsigned* __restrict__ stage) {
    __shared__ int hcnt[NBKT];
    __shared__ int hbase[NBKT];
    int e0 = blockIdx.x * NEPB;
    hcnt[threadIdx.x] = 0;
    __syncthreads();
    const int4* d4 = (const int4*)(dst + e0);
    for (int i = threadIdx.x; i < NEPB / 4; i += 256) {
        int4 d = d4[i];
        atomicAdd(&hcnt[d.x / BKTN], 1);
        atomicAdd(&hcnt[d.y / BKTN], 1);
        atomicAdd(&hcnt[d.z / BKTN], 1);
        atomicAdd(&hcnt[d.w / BKTN], 1);
    }
    __syncthreads();
    hbase[threadIdx.x] = atomicAdd(&gcursor[threadIdx.x], hcnt[threadIdx.x]);
    hcnt[threadIdx.x] = 0;
    __syncthreads();
    const int4* s4 = (const int4*)(src + e0);
    for (int i = threadIdx.x; i < NEPB / 4; i += 256) {
        int4 d = d4[i];
        int4 s = s4[i];
        int ds[4] = {d.x, d.y, d.z, d.w};
        int ss[4] = {s.x, s.y, s.z, s.w};
#pragma unroll
        for (int j = 0; j < 4; j++) {
            int bkt = ds[j] / BKTN;
            int dloc = ds[j] - bkt * BKTN;
            int k = atomicAdd(&hcnt[bkt], 1);
            stage[hbase[bkt] + k] = ((unsigned)dloc << 18) | (unsigned)ss[j];
        }
    }
}

// ---- pass 2: per-bucket count + scan + scatter into compact CSR;
// bucket base inline; also emits dt1 = dis * x (fp32, no W yet) ----
__global__ __launch_bounds__(256) void k_pass2(
        const unsigned* __restrict__ stage, const int* __restrict__ gcursor,
        int* __restrict__ rowptr, int* __restrict__ cnt, int* __restrict__ csr,
        const float* __restrict__ x, float4* __restrict__ dt1) {
    __shared__ int lcnt[BKTN];
    __shared__ int lpos[BKTN];
    __shared__ int partial[256];
    __shared__ int sbase;
    int t = threadIdx.x;
    int bkt = blockIdx.x;
    // bucket-base scan (replicated per block)
    int tot = gcursor[t] - t * BKTCAP;
    partial[t] = tot;
    __syncthreads();
#pragma unroll
    for (int off = 1; off < 256; off <<= 1) {
        int u = (t >= off) ? partial[t - off] : 0;
        __syncthreads();
        partial[t] += u;
        __syncthreads();
    }
    if (t == 0) sbase = (bkt == 0) ? 0 : partial[bkt - 1];
    __syncthreads();
    int base = sbase;
    int n0 = bkt * BKTN;
    int ncnt = (NA - n0 < BKTN) ? (NA - n0) : BKTN;
    int eBeg = bkt * BKTCAP;
    int eCnt = gcursor[bkt] - eBeg;
    for (int i = t; i < BKTN; i += 256) lcnt[i] = 0;
    __syncthreads();
    for (int i = t; i < eCnt; i += 256)
        atomicAdd(&lcnt[stage[eBeg + i] >> 18], 1);
    __syncthreads();
    // node scan: thread t owns nodes [4t, 4t+4)
    int mysum = 0;
#pragma unroll
    for (int j = 0; j < 4; j++) {
        int node = 4 * t + j;
        if (node < ncnt) mysum += lcnt[node];
    }
    partial[t] = mysum;
    __syncthreads();
#pragma unroll
    for (int off = 1; off < 256; off <<= 1) {
        int u = (t >= off) ? partial[t - off] : 0;
        __syncthreads();
        partial[t] += u;
        __syncthreads();
    }
    int running = partial[t] - mysum;
#pragma unroll
    for (int j = 0; j < 4; j++) {
        int node = 4 * t + j;
        if (node < ncnt) {
            lpos[node] = running;
            rowptr[n0 + node] = base + running;
            cnt[n0 + node] = lcnt[node];
            running += lcnt[node];
        }
    }
    __syncthreads();
    for (int i = t; i < eCnt; i += 256) {
        unsigned v = stage[eBeg + i];
        int dloc = v >> 18;
        int s = v & 0x3FFFF;
        int k = atomicAdd(&lpos[dloc], 1);
        csr[base + k] = s;
    }
    // dt1 = dis * x (lcnt stable; no barrier needed)
    for (int i = t; i < ncnt; i += 256) {
        int n = n0 + i;
        float4 p = ((const float4*)x)[n];
        float dv = rsqrtf((float)lcnt[i] + 1.0f);
        dt1[n] = make_float4(dv * p.x, dv * p.y, dv * p.z, dv * p.w);
    }
}

// ---------------- conv1 device body (untiled, transpose load) --------------
template<int CIN, int COUT, int OBLK, int LIN, int PITCH, int POUT, int NTT>
__device__ __forceinline__ void dev_conv1(int b, int oy,
        const float* __restrict__ in, const float* __restrict__ Kw,
        const float* __restrict__ bias, float* __restrict__ out) {
    constexpr int SPO = 256 / OBLK;
    constexpr int PT = (NTT < 4) ? NTT : 4;
    constexpr int NPASS = (NTT + PT - 1) / PT;
    __shared__ __align__(16) float s_in[CIN * PITCH];
    for (int idx = threadIdx.x; idx < CIN * PITCH; idx += 256) s_in[idx] = 0.f;
    __syncthreads();
    for (int idx = threadIdx.x; idx < LIN * CIN; idx += 256) {
        int p = idx / CIN, c = idx - p * CIN;
        s_in[c * PITCH + p] = in[(size_t)b * (LIN * CIN) + idx];
    }
    __syncthreads();
    int ol = threadIdx.x / SPO;
    int s  = threadIdx.x - ol * SPO;
    int o  = oy * OBLK + ol;
    float bo = bias[o];
    const float* wrow = Kw + (size_t)o * CIN * 8;
    for (int pass = 0; pass < NPASS; pass++) {
        float acc[PT][12];
#pragma unroll
        for (int tt = 0; tt < PT; tt++)
#pragma unroll
            for (int j = 0; j < 12; j++) acc[tt][j] = 0.f;
        bool vld[PT]; int tgs[PT];
#pragma unroll
        for (int tt = 0; tt < PT; tt++) {
            int ta = pass * PT + tt;
            int tg = s + SPO * ta;
            tgs[tt] = tg;
            vld[tt] = (ta < NTT) && (4 * tg < POUT);
        }
        for (int i = 0; i < CIN; i++) {
            float wa[8];
            const float4* wp = (const float4*)(wrow + (size_t)i * 8);
            *(float4*)&wa[0] = wp[0];
            *(float4*)&wa[4] = wp[1];
#pragma unroll
            for (int tt = 0; tt < PT; tt++) {
                if (vld[tt]) {
                    const float4* xr = (const float4*)&s_in[i * PITCH + 12 * tgs[tt]];
                    float xa[20];
#pragma unroll
                    for (int q = 0; q < 5; q++) *(float4*)&xa[4 * q] = xr[q];
#pragma unroll
                    for (int j = 0; j < 12; j++) {
                        float sm = acc[tt][j];
#pragma unroll
                        for (int k = 0; k < 8; k++) sm = fmaf(xa[j + k], wa[k], sm);
                        acc[tt][j] = sm;
                    }
                }
            }
        }
#pragma unroll
        for (int tt = 0; tt < PT; tt++) {
            if (vld[tt]) {
#pragma unroll
                for (int p = 0; p < 4; p++) {
                    int P = 4 * tgs[tt] + p;
                    if (P < POUT) {
                        float m = fmaxf(fmaxf(acc[tt][3 * p], acc[tt][3 * p + 1]), acc[tt][3 * p + 2]);
                        out[((size_t)b * COUT + o) * POUT + P] = fmaxf(m + bo, 0.f);
                    }
                }
            }
        }
    }
}

// ------------- tiled conv device body (seq-axis tiles, small LDS) ----------
template<int CIN, int COUT, int OBLK, int LIN, int PITCH, int TPOOL, int POUT>
__device__ __forceinline__ void dev_conv_t(int b, int oy, int tile,
        const float* __restrict__ in, const float* __restrict__ Kw,
        const float* __restrict__ bias, float* __restrict__ out) {
    constexpr int SPO = 256 / OBLK;
    constexpr int NQ = TPOOL / 4;
    constexpr int NTT = (NQ + SPO - 1) / SPO;
    constexpr int SPAN = 3 * TPOOL + 7;
    __shared__ __align__(16) float s_in[CIN * PITCH];
    int p0 = tile * TPOOL;
    int cbase = 3 * p0;
    for (int idx = threadIdx.x; idx < CIN * PITCH; idx += 256) {
        int c = idx / PITCH, p = idx - c * PITCH;
        int gp = cbase + p;
        float v = 0.f;
        if (p < SPAN && gp < LIN) v = in[((size_t)b * CIN + c) * LIN + gp];
        s_in[idx] = v;
    }
    __syncthreads();
    int ol = threadIdx.x / SPO;
    int s  = threadIdx.x - ol * SPO;
    int o  = oy * OBLK + ol;
    float bo = bias[o];
    const float* wrow = Kw + (size_t)o * CIN * 8;
    float acc[NTT][12];
#pragma unroll
    for (int tt = 0; tt < NTT; tt++)
#pragma unroll
        for (int j = 0; j < 12; j++) acc[tt][j] = 0.f;
    bool vld[NTT]; int qgs[NTT];
#pragma unroll
    for (int tt = 0; tt < NTT; tt++) {
        int qg = s + SPO * tt;
        qgs[tt] = qg;
        vld[tt] = (qg < NQ) && (p0 + 4 * qg < POUT);
    }
    for (int i = 0; i < CIN; i++) {
        float wa[8];
        const float4* wp = (const float4*)(wrow + (size_t)i * 8);
        *(float4*)&wa[0] = wp[0];
        *(float4*)&wa[4] = wp[1];
#pragma unroll
        for (int tt = 0; tt < NTT; tt++) {
            if (vld[tt]) {
                const float4* xr = (const float4*)&s_in[i * PITCH + 12 * qgs[tt]];
                float xa[20];
#pragma unroll
                for (int q = 0; q < 5; q++) *(float4*)&xa[4 * q] = xr[q];
#pragma unroll
                for (int j = 0; j < 12; j++) {
                    float sm = acc[tt][j];
#pragma unroll
                    for (int k = 0; k < 8; k++) sm = fmaf(xa[j + k], wa[k], sm);
                    acc[tt][j] = sm;
                }
            }
        }
    }
#pragma unroll
    for (int tt = 0; tt < NTT; tt++) {
        if (vld[tt]) {
#pragma unroll
            for (int p = 0; p < 4; p++) {
                int P = p0 + 4 * qgs[tt] + p;
                if (P < POUT) {
                    float m = fmaxf(fmaxf(acc[tt][3 * p], acc[tt][3 * p + 1]), acc[tt][3 * p + 2]);
                    out[((size_t)b * COUT + o) * POUT + P] = fmaxf(m + bo, 0.f);
                }
            }
        }
    }
}

// -------- K_B: conv1 (1024) || gather1 over dt1 + W1 epilogue (782) --------
// agg = dt1[n] + sum dt1[src]; out1 = relu(dv*(agg@W1)+b1); dt2 = dv*out1
__global__ __launch_bounds__(256) void k_fused_B(
        const float* __restrict__ tgt, const float* __restrict__ K1,
        const float* __restrict__ cb1, float* __restrict__ pool1,
        const float4* __restrict__ dt1, const int* __restrict__ rowptr,
        const int* __restrict__ cnt, const int* __restrict__ csr,
        const float* __restrict__ W1, const float* __restrict__ b1,
        float4* __restrict__ dt2) {
    int bx = blockIdx.x;
    if (bx < 1024) {
        dev_conv1<5, 32, 16, 1000, 1008, 331, 6>(bx & 511, bx >> 9, tgt, K1, cb1, pool1);
        return;
    }
    __shared__ float sW[16];
    if (threadIdx.x < 16) sW[threadIdx.x] = W1[threadIdx.x];
    __syncthreads();
    int n = (bx - 1024) * 256 + threadIdx.x;
    if (n >= NA) return;
    int cn = cnt[n];
    float dv = rsqrtf((float)cn + 1.0f);
    const int* row = csr + rowptr[n];
    float4 acc = dt1[n];
    int e = 0;
    for (; e + 3 < cn; e += 4) {
        int i0 = row[e], i1 = row[e + 1], i2 = row[e + 2], i3 = row[e + 3];
        float4 v0 = dt1[i0], v1 = dt1[i1], v2 = dt1[i2], v3 = dt1[i3];
        acc.x += (v0.x + v1.x) + (v2.x + v3.x);
        acc.y += (v0.y + v1.y) + (v2.y + v3.y);
        acc.z += (v0.z + v1.z) + (v2.z + v3.z);
        acc.w += (v0.w + v1.w) + (v2.w + v3.w);
    }
    for (; e < cn; e++) {
        float4 v = dt1[row[e]];
        acc.x += v.x; acc.y += v.y; acc.z += v.z; acc.w += v.w;
    }
    const float4 bq = *(const float4*)b1;
    float a[4] = {acc.x, acc.y, acc.z, acc.w};
    float bb[4] = {bq.x, bq.y, bq.z, bq.w};
    float o[4];
#pragma unroll
    for (int f = 0; f < 4; f++) {
        float s = 0.f;
#pragma unroll
        for (int k = 0; k < 4; k++) s = fmaf(a[k], sW[k * 4 + f], s);
        o[f] = dv * fmaxf(fmaf(dv, s, bb[f]), 0.f);   // dt2 = dv*relu(...)
    }
    dt2[n] = make_float4(o[0], o[1], o[2], o[3]);
}

// -------- K_C: conv2 tiled (1536) || gather2 over dt2 + W2 epilogue (782) --
// agg = dt2[n] + sum dt2[src]; out2 = relu(dv*(agg@W2)+b2); dt3 = dv*out2 (8)
__global__ __launch_bounds__(256) void k_fused_C(
        const float* __restrict__ pool1, const float* __restrict__ K2,
        const float* __restrict__ cb2, float* __restrict__ pool2,
        const float4* __restrict__ dt2, const int* __restrict__ rowptr,
        const int* __restrict__ cnt, const int* __restrict__ csr,
        const float* __restrict__ W2, const float* __restrict__ b2,
        float4* __restrict__ dt3) {
    int bx = blockIdx.x;
    if (bx < 1536) {
        dev_conv_t<32, 64, 64, 331, 116, 36, 108>(bx & 511, 0, bx >> 9, pool1, K2, cb2, pool2);
        return;
    }
    __shared__ float sW[32];
    if (threadIdx.x < 32) sW[threadIdx.x] = W2[threadIdx.x];
    __syncthreads();
    int n = (bx - 1536) * 256 + threadIdx.x;
    if (n >= NA) return;
    int cn = cnt[n];
    float dv = rsqrtf((float)cn + 1.0f);
    const int* row = csr + rowptr[n];
    float4 acc = dt2[n];
    int e = 0;
    for (; e + 3 < cn; e += 4) {
        int i0 = row[e], i1 = row[e + 1], i2 = row[e + 2], i3 = row[e + 3];
        float4 v0 = dt2[i0], v1 = dt2[i1], v2 = dt2[i2], v3 = dt2[i3];
        acc.x += (v0.x + v1.x) + (v2.x + v3.x);
        acc.y += (v0.y + v1.y) + (v2.y + v3.y);
        acc.z += (v0.z + v1.z) + (v2.z + v3.z);
        acc.w += (v0.w + v1.w) + (v2.w + v3.w);
    }
    for (; e < cn; e++) {
        float4 v = dt2[row[e]];
        acc.x += v.x; acc.y += v.y; acc.z += v.z; acc.w += v.w;
    }
    float a[4] = {acc.x, acc.y, acc.z, acc.w};
    float o[8];
#pragma unroll
    for (int f = 0; f < 8; f++) {
        float s = 0.f;
#pragma unroll
        for (int k = 0; k < 4; k++) s = fmaf(a[k], sW[k * 8 + f], s);
        o[f] = dv * fmaxf(fmaf(dv, s, b2[f]), 0.f);   // dt3 = dv*relu(...)
    }
    dt3[(size_t)n * 2]     = make_float4(o[0], o[1], o[2], o[3]);
    dt3[(size_t)n * 2 + 1] = make_float4(o[4], o[5], o[6], o[7]);
}

// -------- K_D: conv3 tiled (1024) || gather3 (2 lanes/node) + W3 + segmax --
__global__ __launch_bounds__(256) void k_fused_D(
        const float* __restrict__ pool2, const float* __restrict__ K3,
        const float* __restrict__ cb3, float* __restrict__ pool3,
        const float4* __restrict__ dt3, const int* __restrict__ rowptr,
        const int* __restrict__ cnt, const int* __restrict__ csr,
        const float* __restrict__ W3, const float* __restrict__ b3,
        const int* __restrict__ batch, unsigned* __restrict__ g) {
    int bx = blockIdx.x;
    if (bx < 1024) {
        dev_conv_t<64, 128, 128, 108, 68, 20, 33>(bx & 511, 0, bx >> 9, pool2, K3, cb3, pool3);
        return;
    }
    __shared__ float sW[128];
    __shared__ unsigned sg[32];
    __shared__ int sbmin;
    int id = bx - 1024;                  // 0..1562, 128 nodes per block
    if (threadIdx.x < 128) sW[threadIdx.x] = W3[threadIdx.x];
    if (threadIdx.x < 32) sg[threadIdx.x] = 0u;
    if (threadIdx.x == 0) sbmin = batch[id * 128];
    __syncthreads();
    int t = id * 256 + threadIdx.x;
    int n = t >> 1, q = t & 1;
    if (n < NA) {
        int cn = cnt[n];
        float dv = rsqrtf((float)cn + 1.0f);
        const int* row = csr + rowptr[n];
        float4 acc = dt3[(size_t)n * 2 + q];
        int e = 0;
        for (; e + 3 < cn; e += 4) {
            int i0 = row[e], i1 = row[e + 1], i2 = row[e + 2], i3 = row[e + 3];
            float4 v0 = dt3[(size_t)i0 * 2 + q], v1 = dt3[(size_t)i1 * 2 + q];
            float4 v2 = dt3[(size_t)i2 * 2 + q], v3 = dt3[(size_t)i3 * 2 + q];
            acc.x += (v0.x + v1.x) + (v2.x + v3.x);
            acc.y += (v0.y + v1.y) + (v2.y + v3.y);
            acc.z += (v0.z + v1.z) + (v2.z + v3.z);
            acc.w += (v0.w + v1.w) + (v2.w + v3.w);
        }
        for (; e < cn; e++) {
            float4 v = dt3[(size_t)row[e] * 2 + q];
            acc.x += v.x; acc.y += v.y; acc.z += v.z; acc.w += v.w;
        }
        // exchange halves: lane q holds agg dims [4q..4q+3]
        float a[4] = {acc.x, acc.y, acc.z, acc.w};
        float other[4];
#pragma unroll
        for (int j = 0; j < 4; j++) other[j] = __shfl_xor(a[j], 1, 64);
        float af[8];
        if (q == 0) {
#pragma unroll
            for (int j = 0; j < 4; j++) { af[j] = a[j]; af[4 + j] = other[j]; }
        } else {
#pragma unroll
            for (int j = 0; j < 4; j++) { af[j] = other[j]; af[4 + j] = a[j]; }
        }
        int rb = batch[n] - sbmin;
        if (rb > 1) rb = 1;
#pragma unroll
        for (int j = 0; j < 8; j++) {
            int f = q * 8 + j;
            float s = 0.f;
#pragma unroll
            for (int k = 0; k < 8; k++) s = fmaf(af[k], sW[k * 16 + f], s);
            float r = fmaxf(fmaf(dv, s, b3[f]), 0.f);
            atomicMax(&sg[rb * 16 + f], __float_as_uint(r));
        }
    }
    __syncthreads();
    if (threadIdx.x < 32) {
        unsigned v = sg[threadIdx.x];
        int rb2 = threadIdx.x >> 4, f = threadIdx.x & 15;
        int bbn = sbmin + rb2;
        if (v != 0u && bbn < NB) atomicMax(&g[bbn * 16 + f], v);
    }
}

// -------- head1: (g@Wg1 -> gp1, 256 blk) || (mean->@Wxt -> cx, 64 blk) -----
__global__ __launch_bounds__(256) void k_head1(
        const float* __restrict__ g, const float* __restrict__ Wg1,
        const float* __restrict__ bg1, float* __restrict__ gp1,
        const float* __restrict__ pool3, const float* __restrict__ Wxt,
        const float* __restrict__ bxt, float* __restrict__ cx) {
    int bx = blockIdx.x;
    if (bx < 256) {
        __shared__ float sa[8 * 16];
        int b0 = (bx >> 2) * 8;
        if (threadIdx.x < 128)
            sa[threadIdx.x] = g[b0 * 16 + threadIdx.x];
        __syncthreads();
        int j = (bx & 3) * 256 + threadIdx.x;
        float bj = bg1[j];
        float acc[8];
#pragma unroll
        for (int gg = 0; gg < 8; gg++) acc[gg] = bj;
#pragma unroll
        for (int k = 0; k < 16; k++) {
            float w = Wg1[(size_t)k * 1024 + j];
#pragma unroll
            for (int gg = 0; gg < 8; gg++) acc[gg] = fmaf(sa[gg * 16 + k], w, acc[gg]);
        }
#pragma unroll
        for (int gg = 0; gg < 8; gg++)
            gp1[(size_t)(b0 + gg) * 1024 + j] = fmaxf(acc[gg], 0.f);
    } else {
        __shared__ float sa[8 * 128];
        int b0 = (bx - 256) * 8;
        for (int t = threadIdx.x; t < 8 * 128; t += 256) {
            int gg = t >> 7, k = t & 127;
            const float* r = pool3 + ((size_t)(b0 + gg) * 128 + k) * 33;
            float s = 0.f;
#pragma unroll
            for (int p = 0; p < 33; p++) s += r[p];
            sa[t] = s * (1.f / 33.f);
        }
        __syncthreads();
        int j = threadIdx.x;
        if (j >= 128) return;
        float bj = bxt[j];
        float acc[8];
#pragma unroll
        for (int gg = 0; gg < 8; gg++) acc[gg] = bj;
#pragma unroll 4
        for (int k = 0; k < 128; k++) {
            float w = Wxt[(size_t)k * 128 + j];
#pragma unroll
            for (int gg = 0; gg < 8; gg++) acc[gg] = fmaf(sa[gg * 128 + k], w, acc[gg]);
        }
#pragma unroll
        for (int gg = 0; gg < 8; gg++)
            cx[(size_t)(b0 + gg) * 128 + j] = fmaxf(acc[gg], 0.f);
    }
}

// ------- batch-grouped dense: BGRP rows share one pass over W --------------
template<int K, int BGRP, bool RELU>
__global__ __launch_bounds__(256) void k_dense_g(
        const float* __restrict__ A, const float* __restrict__ W,
        const float* __restrict__ bias, float* __restrict__ out, int ncols) {
    __shared__ float sa[BGRP * K];
    int b0 = blockIdx.y * BGRP;
    for (int t = threadIdx.x; t < BGRP * K; t += 256) {
        int gg = t / K, k = t - gg * K;
        sa[t] = A[(size_t)(b0 + gg) * K + k];
    }
    __syncthreads();
    int j = blockIdx.x * 256 + threadIdx.x;
    if (j >= ncols) return;
    float bj = bias[j];
    float acc[BGRP];
#pragma unroll
    for (int gg = 0; gg < BGRP; gg++) acc[gg] = bj;
#pragma unroll 4
    for (int k = 0; k < K; k++) {
        float w = W[(size_t)k * ncols + j];
#pragma unroll
        for (int gg = 0; gg < BGRP; gg++) acc[gg] = fmaf(sa[gg * K + k], w, acc[gg]);
    }
#pragma unroll
    for (int gg = 0; gg < BGRP; gg++) {
        float v = acc[gg];
        if (RELU) v = fmaxf(v, 0.f);
        out[(size_t)(b0 + gg) * ncols + j] = v;
    }
}

// dense with concatenated input [A1 | A2]
template<int KA, int KB2, int BGRP, bool RELU>
__global__ __launch_bounds__(256) void k_dense_cat_g(
        const float* __restrict__ A1, const float* __restrict__ A2,
        const float* __restrict__ W, const float* __restrict__ bias,
        float* __restrict__ out, int ncols) {
    constexpr int K = KA + KB2;
    __shared__ float sa[BGRP * K];
    int b0 = blockIdx.y * BGRP;
    for (int t = threadIdx.x; t < BGRP * K; t += 256) {
        int gg = t / K, k = t - gg * K;
        sa[t] = (k < KA) ? A1[(size_t)(b0 + gg) * KA + k]
                         : A2[(size_t)(b0 + gg) * KB2 + (k - KA)];
    }
    __syncthreads();
    int j = blockIdx.x * 256 + threadIdx.x;
    if (j >= ncols) return;
    float bj = bias[j];
    float acc[BGRP];
#pragma unroll
    for (int gg = 0; gg < BGRP; gg++) acc[gg] = bj;
#pragma unroll 4
    for (int k = 0; k < K; k++) {
        float w = W[(size_t)k * ncols + j];
#pragma unroll
        for (int gg = 0; gg < BGRP; gg++) acc[gg] = fmaf(sa[gg * K + k], w, acc[gg]);
    }
#pragma unroll
    for (int gg = 0; gg < BGRP; gg++) {
        float v = acc[gg];
        if (RELU) v = fmaxf(v, 0.f);
        out[(size_t)(b0 + gg) * ncols + j] = v;
    }
}

// final 512->2 layer
__global__ __launch_bounds__(256) void k_dense_out(
        const float* __restrict__ A, const float* __restrict__ W,
        const float* __restrict__ bias, float* __restrict__ out) {
    int idx = blockIdx.x * 256 + threadIdx.x;
    if (idx >= NB * 2) return;
    int b = idx >> 1, j = idx & 1;
    float s = bias[j];
#pragma unroll 8
    for (int k = 0; k < 512; k++) s = fmaf(A[b * 512 + k], W[k * 2 + j], s);
    out[idx] = s;
}

extern "C" void kernel_launch(void* const* d_in, const int* in_sizes, int n_in,
                              void* d_out, int out_size, void* d_ws, size_t ws_size,
                              hipStream_t stream) {
    (void)in_sizes; (void)n_in; (void)out_size; (void)ws_size;
    const float* x   = (const float*)d_in[0];
    const int*  ei   = (const int*)d_in[1];
    const int*  batch= (const int*)d_in[2];
    const float* tgt = (const float*)d_in[3];
    const float* W1  = (const float*)d_in[4];  const float* b1  = (const float*)d_in[5];
    const float* W2  = (const float*)d_in[6];  const float* b2  = (const float*)d_in[7];
    const float* W3  = (const float*)d_in[8];  const float* b3  = (const float*)d_in[9];
    const float* Wg1 = (const float*)d_in[10]; const float* bg1 = (const float*)d_in[11];
    const float* Wg2 = (const float*)d_in[12]; const float* bg2 = (const float*)d_in[13];
    const float* K1  = (const float*)d_in[14]; const float* cb1 = (const float*)d_in[15];
    const float* K2  = (const float*)d_in[16]; const float* cb2 = (const float*)d_in[17];
    const float* K3  = (const float*)d_in[18]; const float* cb3 = (const float*)d_in[19];
    const float* Wxt = (const float*)d_in[20]; const float* bxt = (const float*)d_in[21];
    const float* Wf1 = (const float*)d_in[22]; const float* bf1 = (const float*)d_in[23];
    const float* Wf2 = (const float*)d_in[24]; const float* bf2 = (const float*)d_in[25];
    const float* Wo  = (const float*)d_in[26]; const float* bo  = (const float*)d_in[27];
    const int* srcp = ei;        // edge_index[0]
    const int* dstp = ei + NE;   // edge_index[1]

    float* ws = (float*)d_ws;
    float4* dt1 = (float4*)ws; ws += (size_t)NA * 4;   // dis*x          (3.2 MB)
    float4* dt2 = (float4*)ws; ws += (size_t)NA * 4;   // dis*out1       (3.2 MB)
    float4* dt3 = (float4*)ws; ws += (size_t)NA * 8;   // dis*out2, 8dim (6.4 MB)
    float* g     = ws; ws += NB * 16;
    float* gp1   = ws; ws += NB * 1024;
    float* gvec  = ws; ws += NB * 128;
    float* cx    = ws; ws += NB * 128;
    float* xf1   = ws; ws += NB * 1024;
    float* xf2   = ws; ws += NB * 512;
    float* pool1 = ws; ws += (size_t)NB * 32 * 331;   // 5.42M (stage aliases)
    float* pool2 = ws; ws += (size_t)NB * 64 * 108;   // 3.54M
    float* pool3 = ws; ws += (size_t)NB * 128 * 33;   // 2.16M
    int*   cnt    = (int*)ws; ws += NA;
    int*   rowptr = (int*)ws; ws += NA;
    int*   csr    = (int*)ws; ws += NE;               // compact CSR
    int*   gcursor= (int*)ws; ws += NBKT;

    // stage (4.19M u32) aliases pool1: alive pass1->pass2; pool1 written in K_B.
    unsigned* stage = (unsigned*)pool1;

    dim3 blk(256);

    k_init<<<32, blk, 0, stream>>>((unsigned*)g, gcursor);
    k_pass1<<<1000, blk, 0, stream>>>(srcp, dstp, gcursor, stage);
    k_pass2<<<NBKT, blk, 0, stream>>>(stage, gcursor, rowptr, cnt, csr, x, dt1);

    // K_B: conv1 (1024) || gather1+W1 (782)
    k_fused_B<<<1806, blk, 0, stream>>>(tgt, K1, cb1, pool1,
                                        dt1, rowptr, cnt, csr, W1, b1, dt2);
    // K_C: conv2 tiled (1536) || gather2+W2 (782)
    k_fused_C<<<2318, blk, 0, stream>>>(pool1, K2, cb2, pool2,
                                        dt2, rowptr, cnt, csr, W2, b2, dt3);
    // K_D: conv3 tiled (1024) || gather3+W3+segmax (1563)
    k_fused_D<<<2587, blk, 0, stream>>>(pool2, K3, cb3, pool3,
                                        dt3, rowptr, cnt, csr, W3, b3,
                                        batch, (unsigned*)g);

    // dense head
    k_head1<<<320, blk, 0, stream>>>(g, Wg1, bg1, gp1, pool3, Wxt, bxt, cx);
    k_dense_g<1024, 8, false><<<dim3(1, 64), blk, 0, stream>>>(gp1, Wg2, bg2, gvec, 128);
    k_dense_cat_g<128, 128, 8, true><<<dim3(4, 64), blk, 0, stream>>>(gvec, cx, Wf1, bf1, xf1, 1024);
    k_dense_g<1024, 8, true><<<dim3(2, 64), blk, 0, stream>>>(xf1, Wf2, bf2, xf2, 512);
    k_dense_out<<<4, blk, 0, stream>>>(xf2, Wo, bo, (float*)d_out);
}

// Round 9
// 737.403 us; speedup vs baseline: 1.3889x; 1.1352x over previous
//
#include <hip/hip_runtime.h>
#include <hip/hip_fp16.h>
#include <cstddef>

#define NA 200000
#define NE 3200000
#define NB 512
#define NBKT 256          // dst-range buckets
#define BKTN 782          // nodes per bucket
#define BKTCAP 16384      // stage capacity per bucket (exp 12500, sigma ~111)
#define NEPB 3200         // edges per pass-1 block (1000*3200 = NE)

// ---------------- fp16 helpers ----------------
union UH2 { unsigned u; __half2 h; };
__device__ __forceinline__ float4 h4f(unsigned a, unsigned b) {
    UH2 x, y; x.u = a; y.u = b;
    float2 fa = __half22float2(x.h), fb = __half22float2(y.h);
    return make_float4(fa.x, fa.y, fb.x, fb.y);
}
__device__ __forceinline__ unsigned f2h(float a, float b) {
    UH2 r; r.h = __float22half2_rn(make_float2(a, b));
    return r.u;
}

// ---------------- init: g=0, gcursor[b]=b*BKTCAP ----------------
__global__ void k_init(unsigned* g, int* gcursor) {
    int i = blockIdx.x * blockDim.x + threadIdx.x;
    if (i < NB * 16) g[i] = 0u;
    if (i < NBKT) gcursor[i] = i * BKTCAP;
}

// ---- pass 1: bin edges into 256 dst-range buckets (LDS hist), payload
// (dstLocal<<18 | src), src<2^18; int4-vectorized edge reads ----
__global__ __launch_bounds__(256) void k_pass1(
        const int* __restrict__ src, const int* __restrict__ dst,
        int* __restrict__ gcursor, unsigned* __restrict__ stage) {
    __shared__ int hcnt[NBKT];
    __shared__ int hbase[NBKT];
    int e0 = blockIdx.x * NEPB;
    hcnt[threadIdx.x] = 0;
    __syncthreads();
    const int4* d4 = (const int4*)(dst + e0);
    for (int i = threadIdx.x; i < NEPB / 4; i += 256) {
        int4 d = d4[i];
        atomicAdd(&hcnt[d.x / BKTN], 1);
        atomicAdd(&hcnt[d.y / BKTN], 1);
        atomicAdd(&hcnt[d.z / BKTN], 1);
        atomicAdd(&hcnt[d.w / BKTN], 1);
    }
    __syncthreads();
    hbase[threadIdx.x] = atomicAdd(&gcursor[threadIdx.x], hcnt[threadIdx.x]);
    hcnt[threadIdx.x] = 0;
    __syncthreads();
    const int4* s4 = (const int4*)(src + e0);
    for (int i = threadIdx.x; i < NEPB / 4; i += 256) {
        int4 d = d4[i];
        int4 s = s4[i];
        int ds[4] = {d.x, d.y, d.z, d.w};
        int ss[4] = {s.x, s.y, s.z, s.w};
#pragma unroll
        for (int j = 0; j < 4; j++) {
            int bkt = ds[j] / BKTN;
            int dloc = ds[j] - bkt * BKTN;
            int k = atomicAdd(&hcnt[bkt], 1);
            stage[hbase[bkt] + k] = ((unsigned)dloc << 18) | (unsigned)ss[j];
        }
    }
}

// ---- pass 2: per-bucket count + scan + scatter into compact CSR;
// bucket base inline; also emits dt1 = dis * x (fp32) ----
__global__ __launch_bounds__(256) void k_pass2(
        const unsigned* __restrict__ stage, const int* __restrict__ gcursor,
        int* __restrict__ rowptr, int* __restrict__ cnt, int* __restrict__ csr,
        const float* __restrict__ x, float4* __restrict__ dt1) {
    __shared__ int lcnt[BKTN];
    __shared__ int lpos[BKTN];
    __shared__ int partial[256];
    __shared__ int sbase;
    int t = threadIdx.x;
    int bkt = blockIdx.x;
    int tot = gcursor[t] - t * BKTCAP;
    partial[t] = tot;
    __syncthreads();
#pragma unroll
    for (int off = 1; off < 256; off <<= 1) {
        int u = (t >= off) ? partial[t - off] : 0;
        __syncthreads();
        partial[t] += u;
        __syncthreads();
    }
    if (t == 0) sbase = (bkt == 0) ? 0 : partial[bkt - 1];
    __syncthreads();
    int base = sbase;
    int n0 = bkt * BKTN;
    int ncnt = (NA - n0 < BKTN) ? (NA - n0) : BKTN;
    int eBeg = bkt * BKTCAP;
    int eCnt = gcursor[bkt] - eBeg;
    for (int i = t; i < BKTN; i += 256) lcnt[i] = 0;
    __syncthreads();
    for (int i = t; i < eCnt; i += 256)
        atomicAdd(&lcnt[stage[eBeg + i] >> 18], 1);
    __syncthreads();
    int mysum = 0;
#pragma unroll
    for (int j = 0; j < 4; j++) {
        int node = 4 * t + j;
        if (node < ncnt) mysum += lcnt[node];
    }
    partial[t] = mysum;
    __syncthreads();
#pragma unroll
    for (int off = 1; off < 256; off <<= 1) {
        int u = (t >= off) ? partial[t - off] : 0;
        __syncthreads();
        partial[t] += u;
        __syncthreads();
    }
    int running = partial[t] - mysum;
#pragma unroll
    for (int j = 0; j < 4; j++) {
        int node = 4 * t + j;
        if (node < ncnt) {
            lpos[node] = running;
            rowptr[n0 + node] = base + running;
            cnt[n0 + node] = lcnt[node];
            running += lcnt[node];
        }
    }
    __syncthreads();
    for (int i = t; i < eCnt; i += 256) {
        unsigned v = stage[eBeg + i];
        int dloc = v >> 18;
        int s = v & 0x3FFFF;
        int k = atomicAdd(&lpos[dloc], 1);
        csr[base + k] = s;
    }
    for (int i = t; i < ncnt; i += 256) {
        int n = n0 + i;
        float4 p = ((const float4*)x)[n];
        float dv = rsqrtf((float)lcnt[i] + 1.0f);
        dt1[n] = make_float4(dv * p.x, dv * p.y, dv * p.z, dv * p.w);
    }
}

// ---------------- conv1 device body (untiled, transpose load) --------------
template<int CIN, int COUT, int OBLK, int LIN, int PITCH, int POUT, int NTT>
__device__ __forceinline__ void dev_conv1(int b, int oy,
        const float* __restrict__ in, const float* __restrict__ Kw,
        const float* __restrict__ bias, float* __restrict__ out) {
    constexpr int SPO = 256 / OBLK;
    constexpr int PT = (NTT < 4) ? NTT : 4;
    constexpr int NPASS = (NTT + PT - 1) / PT;
    __shared__ __align__(16) float s_in[CIN * PITCH];
    for (int idx = threadIdx.x; idx < CIN * PITCH; idx += 256) s_in[idx] = 0.f;
    __syncthreads();
    for (int idx = threadIdx.x; idx < LIN * CIN; idx += 256) {
        int p = idx / CIN, c = idx - p * CIN;
        s_in[c * PITCH + p] = in[(size_t)b * (LIN * CIN) + idx];
    }
    __syncthreads();
    int ol = threadIdx.x / SPO;
    int s  = threadIdx.x - ol * SPO;
    int o  = oy * OBLK + ol;
    float bo = bias[o];
    const float* wrow = Kw + (size_t)o * CIN * 8;
    for (int pass = 0; pass < NPASS; pass++) {
        float acc[PT][12];
#pragma unroll
        for (int tt = 0; tt < PT; tt++)
#pragma unroll
            for (int j = 0; j < 12; j++) acc[tt][j] = 0.f;
        bool vld[PT]; int tgs[PT];
#pragma unroll
        for (int tt = 0; tt < PT; tt++) {
            int ta = pass * PT + tt;
            int tg = s + SPO * ta;
            tgs[tt] = tg;
            vld[tt] = (ta < NTT) && (4 * tg < POUT);
        }
        for (int i = 0; i < CIN; i++) {
            float wa[8];
            const float4* wp = (const float4*)(wrow + (size_t)i * 8);
            *(float4*)&wa[0] = wp[0];
            *(float4*)&wa[4] = wp[1];
#pragma unroll
            for (int tt = 0; tt < PT; tt++) {
                if (vld[tt]) {
                    const float4* xr = (const float4*)&s_in[i * PITCH + 12 * tgs[tt]];
                    float xa[20];
#pragma unroll
                    for (int q = 0; q < 5; q++) *(float4*)&xa[4 * q] = xr[q];
#pragma unroll
                    for (int j = 0; j < 12; j++) {
                        float sm = acc[tt][j];
#pragma unroll
                        for (int k = 0; k < 8; k++) sm = fmaf(xa[j + k], wa[k], sm);
                        acc[tt][j] = sm;
                    }
                }
            }
        }
#pragma unroll
        for (int tt = 0; tt < PT; tt++) {
            if (vld[tt]) {
#pragma unroll
                for (int p = 0; p < 4; p++) {
                    int P = 4 * tgs[tt] + p;
                    if (P < POUT) {
                        float m = fmaxf(fmaxf(acc[tt][3 * p], acc[tt][3 * p + 1]), acc[tt][3 * p + 2]);
                        out[((size_t)b * COUT + o) * POUT + P] = fmaxf(m + bo, 0.f);
                    }
                }
            }
        }
    }
}

// ------------- tiled conv device body (seq-axis tiles, small LDS) ----------
template<int CIN, int COUT, int OBLK, int LIN, int PITCH, int TPOOL, int POUT>
__device__ __forceinline__ void dev_conv_t(int b, int oy, int tile,
        const float* __restrict__ in, const float* __restrict__ Kw,
        const float* __restrict__ bias, float* __restrict__ out) {
    constexpr int SPO = 256 / OBLK;
    constexpr int NQ = TPOOL / 4;
    constexpr int NTT = (NQ + SPO - 1) / SPO;
    constexpr int SPAN = 3 * TPOOL + 7;
    __shared__ __align__(16) float s_in[CIN * PITCH];
    int p0 = tile * TPOOL;
    int cbase = 3 * p0;
    for (int idx = threadIdx.x; idx < CIN * PITCH; idx += 256) {
        int c = idx / PITCH, p = idx - c * PITCH;
        int gp = cbase + p;
        float v = 0.f;
        if (p < SPAN && gp < LIN) v = in[((size_t)b * CIN + c) * LIN + gp];
        s_in[idx] = v;
    }
    __syncthreads();
    int ol = threadIdx.x / SPO;
    int s  = threadIdx.x - ol * SPO;
    int o  = oy * OBLK + ol;
    float bo = bias[o];
    const float* wrow = Kw + (size_t)o * CIN * 8;
    float acc[NTT][12];
#pragma unroll
    for (int tt = 0; tt < NTT; tt++)
#pragma unroll
        for (int j = 0; j < 12; j++) acc[tt][j] = 0.f;
    bool vld[NTT]; int qgs[NTT];
#pragma unroll
    for (int tt = 0; tt < NTT; tt++) {
        int qg = s + SPO * tt;
        qgs[tt] = qg;
        vld[tt] = (qg < NQ) && (p0 + 4 * qg < POUT);
    }
    for (int i = 0; i < CIN; i++) {
        float wa[8];
        const float4* wp = (const float4*)(wrow + (size_t)i * 8);
        *(float4*)&wa[0] = wp[0];
        *(float4*)&wa[4] = wp[1];
#pragma unroll
        for (int tt = 0; tt < NTT; tt++) {
            if (vld[tt]) {
                const float4* xr = (const float4*)&s_in[i * PITCH + 12 * qgs[tt]];
                float xa[20];
#pragma unroll
                for (int q = 0; q < 5; q++) *(float4*)&xa[4 * q] = xr[q];
#pragma unroll
                for (int j = 0; j < 12; j++) {
                    float sm = acc[tt][j];
#pragma unroll
                    for (int k = 0; k < 8; k++) sm = fmaf(xa[j + k], wa[k], sm);
                    acc[tt][j] = sm;
                }
            }
        }
    }
#pragma unroll
    for (int tt = 0; tt < NTT; tt++) {
        if (vld[tt]) {
#pragma unroll
            for (int p = 0; p < 4; p++) {
                int P = p0 + 4 * qgs[tt] + p;
                if (P < POUT) {
                    float m = fmaxf(fmaxf(acc[tt][3 * p], acc[tt][3 * p + 1]), acc[tt][3 * p + 2]);
                    out[((size_t)b * COUT + o) * POUT + P] = fmaxf(m + bo, 0.f);
                }
            }
        }
    }
}

// -------- K_B: conv1 (1024) || gather1 over dt1 + W1 epilogue (782) --------
__global__ __launch_bounds__(256) void k_fused_B(
        const float* __restrict__ tgt, const float* __restrict__ K1,
        const float* __restrict__ cb1, float* __restrict__ pool1,
        const float4* __restrict__ dt1, const int* __restrict__ rowptr,
        const int* __restrict__ cnt, const int* __restrict__ csr,
        const float* __restrict__ W1, const float* __restrict__ b1,
        float4* __restrict__ dt2) {
    int bx = blockIdx.x;
    if (bx < 1024) {
        dev_conv1<5, 32, 16, 1000, 1008, 331, 6>(bx & 511, bx >> 9, tgt, K1, cb1, pool1);
        return;
    }
    __shared__ float sW[16];
    if (threadIdx.x < 16) sW[threadIdx.x] = W1[threadIdx.x];
    __syncthreads();
    int n = (bx - 1024) * 256 + threadIdx.x;
    if (n >= NA) return;
    int cn = cnt[n];
    float dv = rsqrtf((float)cn + 1.0f);
    const int* row = csr + rowptr[n];
    float4 acc = dt1[n];
    int e = 0;
    for (; e + 3 < cn; e += 4) {
        int i0 = row[e], i1 = row[e + 1], i2 = row[e + 2], i3 = row[e + 3];
        float4 v0 = dt1[i0], v1 = dt1[i1], v2 = dt1[i2], v3 = dt1[i3];
        acc.x += (v0.x + v1.x) + (v2.x + v3.x);
        acc.y += (v0.y + v1.y) + (v2.y + v3.y);
        acc.z += (v0.z + v1.z) + (v2.z + v3.z);
        acc.w += (v0.w + v1.w) + (v2.w + v3.w);
    }
    for (; e < cn; e++) {
        float4 v = dt1[row[e]];
        acc.x += v.x; acc.y += v.y; acc.z += v.z; acc.w += v.w;
    }
    const float4 bq = *(const float4*)b1;
    float a[4] = {acc.x, acc.y, acc.z, acc.w};
    float bb[4] = {bq.x, bq.y, bq.z, bq.w};
    float o[4];
#pragma unroll
    for (int f = 0; f < 4; f++) {
        float s = 0.f;
#pragma unroll
        for (int k = 0; k < 4; k++) s = fmaf(a[k], sW[k * 4 + f], s);
        o[f] = dv * fmaxf(fmaf(dv, s, bb[f]), 0.f);   // dt2 = dv*relu(...)
    }
    dt2[n] = make_float4(o[0], o[1], o[2], o[3]);
}

// -------- K_C: conv2 tiled (1536) || gather2 over dt2 + W2 epilogue (782) --
// dt3 written as packed fp16 (uint4 = 8 halves = one 16B line per node)
__global__ __launch_bounds__(256) void k_fused_C(
        const float* __restrict__ pool1, const float* __restrict__ K2,
        const float* __restrict__ cb2, float* __restrict__ pool2,
        const float4* __restrict__ dt2, const int* __restrict__ rowptr,
        const int* __restrict__ cnt, const int* __restrict__ csr,
        const float* __restrict__ W2, const float* __restrict__ b2,
        uint4* __restrict__ dt3) {
    int bx = blockIdx.x;
    if (bx < 1536) {
        dev_conv_t<32, 64, 64, 331, 116, 36, 108>(bx & 511, 0, bx >> 9, pool1, K2, cb2, pool2);
        return;
    }
    __shared__ float sW[32];
    if (threadIdx.x < 32) sW[threadIdx.x] = W2[threadIdx.x];
    __syncthreads();
    int n = (bx - 1536) * 256 + threadIdx.x;
    if (n >= NA) return;
    int cn = cnt[n];
    float dv = rsqrtf((float)cn + 1.0f);
    const int* row = csr + rowptr[n];
    float4 acc = dt2[n];
    int e = 0;
    for (; e + 3 < cn; e += 4) {
        int i0 = row[e], i1 = row[e + 1], i2 = row[e + 2], i3 = row[e + 3];
        float4 v0 = dt2[i0], v1 = dt2[i1], v2 = dt2[i2], v3 = dt2[i3];
        acc.x += (v0.x + v1.x) + (v2.x + v3.x);
        acc.y += (v0.y + v1.y) + (v2.y + v3.y);
        acc.z += (v0.z + v1.z) + (v2.z + v3.z);
        acc.w += (v0.w + v1.w) + (v2.w + v3.w);
    }
    for (; e < cn; e++) {
        float4 v = dt2[row[e]];
        acc.x += v.x; acc.y += v.y; acc.z += v.z; acc.w += v.w;
    }
    float a[4] = {acc.x, acc.y, acc.z, acc.w};
    float o[8];
#pragma unroll
    for (int f = 0; f < 8; f++) {
        float s = 0.f;
#pragma unroll
        for (int k = 0; k < 4; k++) s = fmaf(a[k], sW[k * 8 + f], s);
        o[f] = dv * fmaxf(fmaf(dv, s, b2[f]), 0.f);   // dt3 = dv*relu(...)
    }
    dt3[n] = make_uint4(f2h(o[0], o[1]), f2h(o[2], o[3]),
                        f2h(o[4], o[5]), f2h(o[6], o[7]));
}

// -------- K_D: conv3 tiled (1024) || gather3 (1 thread/node, fp16 dt3,
//          L2-resident 3.2MB) + W3 epilogue + segmax (782) ----------------
__global__ __launch_bounds__(256) void k_fused_D(
        const float* __restrict__ pool2, const float* __restrict__ K3,
        const float* __restrict__ cb3, float* __restrict__ pool3,
        const uint4* __restrict__ dt3, const int* __restrict__ rowptr,
        const int* __restrict__ cnt, const int* __restrict__ csr,
        const float* __restrict__ W3, const float* __restrict__ b3,
        const int* __restrict__ batch, unsigned* __restrict__ g) {
    int bx = blockIdx.x;
    if (bx < 1024) {
        dev_conv_t<64, 128, 128, 108, 68, 20, 33>(bx & 511, 0, bx >> 9, pool2, K3, cb3, pool3);
        return;
    }
    __shared__ float sW[128];
    __shared__ unsigned sg[32];
    __shared__ int sbmin;
    int id = bx - 1024;                  // 0..781, 256 nodes per block
    if (threadIdx.x < 128) sW[threadIdx.x] = W3[threadIdx.x];
    if (threadIdx.x < 32) sg[threadIdx.x] = 0u;
    if (threadIdx.x == 0) sbmin = batch[id * 256];
    __syncthreads();
    int n = id * 256 + threadIdx.x;
    if (n < NA) {
        int cn = cnt[n];
        float dv = rsqrtf((float)cn + 1.0f);
        const int* row = csr + rowptr[n];
        uint4 sv = dt3[n];
        float4 lo = h4f(sv.x, sv.y), hi = h4f(sv.z, sv.w);
        float a0 = lo.x, a1 = lo.y, a2 = lo.z, a3 = lo.w;
        float a4 = hi.x, a5 = hi.y, a6 = hi.z, a7 = hi.w;
        int e = 0;
        for (; e + 3 < cn; e += 4) {
            uint4 p0 = dt3[row[e]],     p1 = dt3[row[e + 1]];
            uint4 p2 = dt3[row[e + 2]], p3 = dt3[row[e + 3]];
            float4 l0 = h4f(p0.x, p0.y), h0 = h4f(p0.z, p0.w);
            float4 l1 = h4f(p1.x, p1.y), h1 = h4f(p1.z, p1.w);
            float4 l2 = h4f(p2.x, p2.y), h2 = h4f(p2.z, p2.w);
            float4 l3 = h4f(p3.x, p3.y), h3v = h4f(p3.z, p3.w);
            a0 += (l0.x + l1.x) + (l2.x + l3.x);
            a1 += (l0.y + l1.y) + (l2.y + l3.y);
            a2 += (l0.z + l1.z) + (l2.z + l3.z);
            a3 += (l0.w + l1.w) + (l2.w + l3.w);
            a4 += (h0.x + h1.x) + (h2.x + h3v.x);
            a5 += (h0.y + h1.y) + (h2.y + h3v.y);
            a6 += (h0.z + h1.z) + (h2.z + h3v.z);
            a7 += (h0.w + h1.w) + (h2.w + h3v.w);
        }
        for (; e < cn; e++) {
            uint4 p = dt3[row[e]];
            float4 l = h4f(p.x, p.y), h = h4f(p.z, p.w);
            a0 += l.x; a1 += l.y; a2 += l.z; a3 += l.w;
            a4 += h.x; a5 += h.y; a6 += h.z; a7 += h.w;
        }
        float af[8] = {a0, a1, a2, a3, a4, a5, a6, a7};
        int rb = batch[n] - sbmin;
        if (rb > 1) rb = 1;
#pragma unroll
        for (int f = 0; f < 16; f++) {
            float s = 0.f;
#pragma unroll
            for (int k = 0; k < 8; k++) s = fmaf(af[k], sW[k * 16 + f], s);
            float r = fmaxf(fmaf(dv, s, b3[f]), 0.f);
            atomicMax(&sg[rb * 16 + f], __float_as_uint(r));
        }
    }
    __syncthreads();
    if (threadIdx.x < 32) {
        unsigned v = sg[threadIdx.x];
        int rb2 = threadIdx.x >> 4, f = threadIdx.x & 15;
        int bbn = sbmin + rb2;
        if (v != 0u && bbn < NB) atomicMax(&g[bbn * 16 + f], v);
    }
}

// -------- head1: (g@Wg1 -> gp1, 256 blk) || (mean->@Wxt -> cx, 64 blk) -----
__global__ __launch_bounds__(256) void k_head1(
        const float* __restrict__ g, const float* __restrict__ Wg1,
        const float* __restrict__ bg1, float* __restrict__ gp1,
        const float* __restrict__ pool3, const float* __restrict__ Wxt,
        const float* __restrict__ bxt, float* __restrict__ cx) {
    int bx = blockIdx.x;
    if (bx < 256) {
        __shared__ float sa[8 * 16];
        int b0 = (bx >> 2) * 8;
        if (threadIdx.x < 128)
            sa[threadIdx.x] = g[b0 * 16 + threadIdx.x];
        __syncthreads();
        int j = (bx & 3) * 256 + threadIdx.x;
        float bj = bg1[j];
        float acc[8];
#pragma unroll
        for (int gg = 0; gg < 8; gg++) acc[gg] = bj;
#pragma unroll
        for (int k = 0; k < 16; k++) {
            float w = Wg1[(size_t)k * 1024 + j];
#pragma unroll
            for (int gg = 0; gg < 8; gg++) acc[gg] = fmaf(sa[gg * 16 + k], w, acc[gg]);
        }
#pragma unroll
        for (int gg = 0; gg < 8; gg++)
            gp1[(size_t)(b0 + gg) * 1024 + j] = fmaxf(acc[gg], 0.f);
    } else {
        __shared__ float sa[8 * 128];
        int b0 = (bx - 256) * 8;
        for (int t = threadIdx.x; t < 8 * 128; t += 256) {
            int gg = t >> 7, k = t & 127;
            const float* r = pool3 + ((size_t)(b0 + gg) * 128 + k) * 33;
            float s = 0.f;
#pragma unroll
            for (int p = 0; p < 33; p++) s += r[p];
            sa[t] = s * (1.f / 33.f);
        }
        __syncthreads();
        int j = threadIdx.x;
        if (j >= 128) return;
        float bj = bxt[j];
        float acc[8];
#pragma unroll
        for (int gg = 0; gg < 8; gg++) acc[gg] = bj;
#pragma unroll 4
        for (int k = 0; k < 128; k++) {
            float w = Wxt[(size_t)k * 128 + j];
#pragma unroll
            for (int gg = 0; gg < 8; gg++) acc[gg] = fmaf(sa[gg * 128 + k], w, acc[gg]);
        }
#pragma unroll
        for (int gg = 0; gg < 8; gg++)
            cx[(size_t)(b0 + gg) * 128 + j] = fmaxf(acc[gg], 0.f);
    }
}

// ------- batch-grouped dense: BGRP rows share one pass over W --------------
template<int K, int BGRP, bool RELU>
__global__ __launch_bounds__(256) void k_dense_g(
        const float* __restrict__ A, const float* __restrict__ W,
        const float* __restrict__ bias, float* __restrict__ out, int ncols) {
    __shared__ float sa[BGRP * K];
    int b0 = blockIdx.y * BGRP;
    for (int t = threadIdx.x; t < BGRP * K; t += 256) {
        int gg = t / K, k = t - gg * K;
        sa[t] = A[(size_t)(b0 + gg) * K + k];
    }
    __syncthreads();
    int j = blockIdx.x * 256 + threadIdx.x;
    if (j >= ncols) return;
    float bj = bias[j];
    float acc[BGRP];
#pragma unroll
    for (int gg = 0; gg < BGRP; gg++) acc[gg] = bj;
#pragma unroll 4
    for (int k = 0; k < K; k++) {
        float w = W[(size_t)k * ncols + j];
#pragma unroll
        for (int gg = 0; gg < BGRP; gg++) acc[gg] = fmaf(sa[gg * K + k], w, acc[gg]);
    }
#pragma unroll
    for (int gg = 0; gg < BGRP; gg++) {
        float v = acc[gg];
        if (RELU) v = fmaxf(v, 0.f);
        out[(size_t)(b0 + gg) * ncols + j] = v;
    }
}

// dense with concatenated input [A1 | A2]
template<int KA, int KB2, int BGRP, bool RELU>
__global__ __launch_bounds__(256) void k_dense_cat_g(
        const float* __restrict__ A1, const float* __restrict__ A2,
        const float* __restrict__ W, const float* __restrict__ bias,
        float* __restrict__ out, int ncols) {
    constexpr int K = KA + KB2;
    __shared__ float sa[BGRP * K];
    int b0 = blockIdx.y * BGRP;
    for (int t = threadIdx.x; t < BGRP * K; t += 256) {
        int gg = t / K, k = t - gg * K;
        sa[t] = (k < KA) ? A1[(size_t)(b0 + gg) * KA + k]
                         : A2[(size_t)(b0 + gg) * KB2 + (k - KA)];
    }
    __syncthreads();
    int j = blockIdx.x * 256 + threadIdx.x;
    if (j >= ncols) return;
    float bj = bias[j];
    float acc[BGRP];
#pragma unroll
    for (int gg = 0; gg < BGRP; gg++) acc[gg] = bj;
#pragma unroll 4
    for (int k = 0; k < K; k++) {
        float w = W[(size_t)k * ncols + j];
#pragma unroll
        for (int gg = 0; gg < BGRP; gg++) acc[gg] = fmaf(sa[gg * K + k], w, acc[gg]);
    }
#pragma unroll
    for (int gg = 0; gg < BGRP; gg++) {
        float v = acc[gg];
        if (RELU) v = fmaxf(v, 0.f);
        out[(size_t)(b0 + gg) * ncols + j] = v;
    }
}

// final 512->2 layer
__global__ __launch_bounds__(256) void k_dense_out(
        const float* __restrict__ A, const float* __restrict__ W,
        const float* __restrict__ bias, float* __restrict__ out) {
    int idx = blockIdx.x * 256 + threadIdx.x;
    if (idx >= NB * 2) return;
    int b = idx >> 1, j = idx & 1;
    float s = bias[j];
#pragma unroll 8
    for (int k = 0; k < 512; k++) s = fmaf(A[b * 512 + k], W[k * 2 + j], s);
    out[idx] = s;
}

extern "C" void kernel_launch(void* const* d_in, const int* in_sizes, int n_in,
                              void* d_out, int out_size, void* d_ws, size_t ws_size,
                              hipStream_t stream) {
    (void)in_sizes; (void)n_in; (void)out_size; (void)ws_size;
    const float* x   = (const float*)d_in[0];
    const int*  ei   = (const int*)d_in[1];
    const int*  batch= (const int*)d_in[2];
    const float* tgt = (const float*)d_in[3];
    const float* W1  = (const float*)d_in[4];  const float* b1  = (const float*)d_in[5];
    const float* W2  = (const float*)d_in[6];  const float* b2  = (const float*)d_in[7];
    const float* W3  = (const float*)d_in[8];  const float* b3  = (const float*)d_in[9];
    const float* Wg1 = (const float*)d_in[10]; const float* bg1 = (const float*)d_in[11];
    const float* Wg2 = (const float*)d_in[12]; const float* bg2 = (const float*)d_in[13];
    const float* K1  = (const float*)d_in[14]; const float* cb1 = (const float*)d_in[15];
    const float* K2  = (const float*)d_in[16]; const float* cb2 = (const float*)d_in[17];
    const float* K3  = (const float*)d_in[18]; const float* cb3 = (const float*)d_in[19];
    const float* Wxt = (const float*)d_in[20]; const float* bxt = (const float*)d_in[21];
    const float* Wf1 = (const float*)d_in[22]; const float* bf1 = (const float*)d_in[23];
    const float* Wf2 = (const float*)d_in[24]; const float* bf2 = (const float*)d_in[25];
    const float* Wo  = (const float*)d_in[26]; const float* bo  = (const float*)d_in[27];
    const int* srcp = ei;        // edge_index[0]
    const int* dstp = ei + NE;   // edge_index[1]

    float* ws = (float*)d_ws;
    float4* dt1 = (float4*)ws; ws += (size_t)NA * 4;   // dis*x          (3.2 MB)
    float4* dt2 = (float4*)ws; ws += (size_t)NA * 4;   // dis*out1       (3.2 MB)
    uint4*  dt3 = (uint4*)ws;  ws += (size_t)NA * 4;   // dis*out2 fp16  (3.2 MB)
    float* g     = ws; ws += NB * 16;
    float* gp1   = ws; ws += NB * 1024;
    float* gvec  = ws; ws += NB * 128;
    float* cx    = ws; ws += NB * 128;
    float* xf1   = ws; ws += NB * 1024;
    float* xf2   = ws; ws += NB * 512;
    float* pool1 = ws; ws += (size_t)NB * 32 * 331;   // 5.42M (stage aliases)
    float* pool2 = ws; ws += (size_t)NB * 64 * 108;   // 3.54M
    float* pool3 = ws; ws += (size_t)NB * 128 * 33;   // 2.16M
    int*   cnt    = (int*)ws; ws += NA;
    int*   rowptr = (int*)ws; ws += NA;
    int*   csr    = (int*)ws; ws += NE;               // compact CSR
    int*   gcursor= (int*)ws; ws += NBKT;

    // stage (4.19M u32) aliases pool1: alive pass1->pass2; pool1 written in K_B.
    unsigned* stage = (unsigned*)pool1;

    dim3 blk(256);

    k_init<<<32, blk, 0, stream>>>((unsigned*)g, gcursor);
    k_pass1<<<1000, blk, 0, stream>>>(srcp, dstp, gcursor, stage);
    k_pass2<<<NBKT, blk, 0, stream>>>(stage, gcursor, rowptr, cnt, csr, x, dt1);

    // K_B: conv1 (1024) || gather1+W1 (782)
    k_fused_B<<<1806, blk, 0, stream>>>(tgt, K1, cb1, pool1,
                                        dt1, rowptr, cnt, csr, W1, b1, dt2);
    // K_C: conv2 tiled (1536) || gather2+W2 (782)
    k_fused_C<<<2318, blk, 0, stream>>>(pool1, K2, cb2, pool2,
                                        dt2, rowptr, cnt, csr, W2, b2, dt3);
    // K_D: conv3 tiled (1024) || gather3(fp16,1thr/node)+W3+segmax (782)
    k_fused_D<<<1806, blk, 0, stream>>>(pool2, K3, cb3, pool3,
                                        dt3, rowptr, cnt, csr, W3, b3,
                                        batch, (unsigned*)g);

    // dense head
    k_head1<<<320, blk, 0, stream>>>(g, Wg1, bg1, gp1, pool3, Wxt, bxt, cx);
    k_dense_g<1024, 8, false><<<dim3(1, 64), blk, 0, stream>>>(gp1, Wg2, bg2, gvec, 128);
    k_dense_cat_g<128, 128, 8, true><<<dim3(4, 64), blk, 0, stream>>>(gvec, cx, Wf1, bf1, xf1, 1024);
    k_dense_g<1024, 8, true><<<dim3(2, 64), blk, 0, stream>>>(xf1, Wf2, bf2, xf2, 512);
    k_dense_out<<<4, blk, 0, stream>>>(xf2, Wo, bo, (float*)d_out);
}